// Round 5
// baseline (710.941 us; speedup 1.0000x reference)
//
#include <hip/hip_runtime.h>
#include <cstdint>

// Problem constants (fixed by reference):
#define Bc 1024
#define Tc 4096
#define Nc 2048
#define Kc 16
#define Mc 65536

#define Gn 2               // memory rows per block in probe kernel
#define GRID_B (Nc / Gn)   // 1024 blocks = 4 per CU (16 waves/CU streaming)

// clang ext_vector types (HIP_vector_type int4 is NOT accepted by
// __builtin_nontemporal_load/store).
typedef int  v4i  __attribute__((ext_vector_type(4)));
typedef int  v2i  __attribute__((ext_vector_type(2)));

// ---------------------------------------------------------------------------
// Kernel A (b-major): compute all 16-bit addresses, store u16 to workspace.
// Verified in round 4 (absmax 0). Unchanged.
// ---------------------------------------------------------------------------
__global__ __launch_bounds__(256) void addr_kernel(
    const int* __restrict__ input_bits,     // (B, T)
    const int* __restrict__ connections,    // (N, K)
    unsigned short* __restrict__ addr)      // (B, N) u16
{
    __shared__ uint32_t bits[Tc / 32];      // 512 B

    const int b    = blockIdx.x;
    const int tid  = threadIdx.x;
    const int lane = tid & 63;
    const int wave = tid >> 6;

    const int* row = input_bits + (size_t)b * Tc;

#pragma unroll
    for (int i = 0; i < Tc / 256; ++i) {    // 16 iterations
        const int pos = i * 256 + wave * 64 + lane;
        const unsigned long long m = __ballot(row[pos] & 1);
        if (lane == 0) {
            const int w64 = i * 4 + wave;
            bits[w64 * 2]     = (uint32_t)m;
            bits[w64 * 2 + 1] = (uint32_t)(m >> 32);
        }
    }
    __syncthreads();

#pragma unroll
    for (int i = 0; i < Nc / 256; ++i) {    // 8 iterations
        const int n = i * 256 + tid;
        const int4* cp = (const int4*)(connections + n * Kc);
        const int4 c0 = cp[0], c1 = cp[1], c2 = cp[2], c3 = cp[3];
        const int c[16] = {c0.x, c0.y, c0.z, c0.w,
                           c1.x, c1.y, c1.z, c1.w,
                           c2.x, c2.y, c2.z, c2.w,
                           c3.x, c3.y, c3.z, c3.w};
        uint32_t a = 0;
#pragma unroll
        for (int k = 0; k < 16; ++k) {
            const uint32_t t = (uint32_t)c[k];
            a |= ((bits[t >> 5] >> (t & 31)) & 1u) << k;
        }
        addr[(size_t)b * Nc + n] = (unsigned short)a;   // coalesced 128B/wave
    }
}

// ---------------------------------------------------------------------------
// Kernel B (n-major): each block owns Gn=2 memory rows (512 KB raw).
// Phase 1 streams the rows coalesced and ballot-packs bit0 into a 16 KB LDS
// bitset (layout bit-identical to the round-4 verified version).
// Phase 2 probes LDS for all 1024 batches.
//
// Occupancy: 16 KB LDS -> 4 blocks/CU -> 16 waves/CU; 16 waves x 8 KB
// outstanding = 128 KB in flight per CU >> BW*latency (~9 KB). Block-start
// stagger decorrelates HBM channel access across the 1024 lockstep blocks.
//
// Packed layout (matches wave ballot order):
//   chunk q = 256 elements. Element e in chunk: lane l = e>>2, comp c = e&3.
//   word index within row = (q&255)*8 + c*2 + (l>>5), bit = l&31.
//   Probe addr a: idx = (a>>8)*8 + (a&3)*2 + ((a>>7)&1); bit = (a>>2)&31.
// ---------------------------------------------------------------------------
__global__ __launch_bounds__(256) void probe_kernel(
    const int* __restrict__ memory,          // (N, M)
    const unsigned short* __restrict__ addr, // (B, N)
    int* __restrict__ out)                   // (B, N) bool-as-int32
{
    __shared__ uint32_t prow[Gn][Mc / 32];   // 2 x 2048 words = 16 KB

    const int n0   = blockIdx.x * Gn;
    const int tid  = threadIdx.x;
    const int lane = tid & 63;
    const int wave = tid >> 6;

    // ---- Phase 1: stream + ballot-pack ----
    // 512 chunks total; wave w owns [w*128, (w+1)*128), 16 iters x 8 chunks.
    const int stag = blockIdx.x & 15;        // stagger start within the range
    for (int jj = 0; jj < 16; ++jj) {
        const int j  = (jj + stag) & 15;
        const int qb = wave * 128 + j * 8;   // this wave's 8 chunks
        v4i v[8];
#pragma unroll
        for (int u = 0; u < 8; ++u) {        // 8 independent loads in flight
            const int q  = qb + u;
            const int r  = q >> 8;           // row in group (0..1)
            const int it = q & 255;          // chunk within row
            v[u] = __builtin_nontemporal_load(
                (const v4i*)(memory + (size_t)(n0 + r) * Mc) + it * 64 + lane);
        }
#pragma unroll
        for (int u = 0; u < 8; ++u) {
            const int q = qb + u;
            const unsigned long long m0 = __ballot(v[u].x & 1);
            const unsigned long long m1 = __ballot(v[u].y & 1);
            const unsigned long long m2 = __ballot(v[u].z & 1);
            const unsigned long long m3 = __ballot(v[u].w & 1);
            if (lane < 8) {
                const int c = lane >> 1;
                const unsigned long long mm =
                    (c == 0) ? m0 : (c == 1) ? m1 : (c == 2) ? m2 : m3;
                prow[q >> 8][(q & 255) * 8 + lane] =
                    (uint32_t)(mm >> ((lane & 1) << 5));
            }
        }
    }
    __syncthreads();

    // ---- Phase 2: probe LDS for all 1024 b's (2 n's per thread-iter) ----
#pragma unroll
    for (int j = 0; j < 4; ++j) {
        const int b = j * 256 + tid;
        // addr[b][n0] and addr[b][n0+1] in one aligned u32 (n0 is even)
        const uint32_t av = *(const uint32_t*)(addr + (size_t)b * Nc + n0);
        const uint32_t a0 = av & 0xffffu;
        const uint32_t a1 = av >> 16;
        const uint32_t i0 = ((a0 >> 8) << 3) + ((a0 & 3) << 1) + ((a0 >> 7) & 1);
        const uint32_t i1 = ((a1 >> 8) << 3) + ((a1 & 3) << 1) + ((a1 >> 7) & 1);
        v2i r;
        r.x = (int)((prow[0][i0] >> ((a0 >> 2) & 31)) & 1u);
        r.y = (int)((prow[1][i1] >> ((a1 >> 2) & 31)) & 1u);
        __builtin_nontemporal_store(r, (v2i*)(out + (size_t)b * Nc + n0));
    }
}

// ---------------------------------------------------------------------------
// Fallback (original verified kernel) in case ws_size < 4 MB.
// ---------------------------------------------------------------------------
__global__ __launch_bounds__(256) void ram_lookup_fused(
    const int* __restrict__ input_bits,
    const int* __restrict__ connections,
    const int* __restrict__ memory,
    int* __restrict__ out)
{
    __shared__ uint32_t bits[Tc / 32];

    const int b    = blockIdx.x;
    const int tid  = threadIdx.x;
    const int lane = tid & 63;
    const int wave = tid >> 6;

    const int* row = input_bits + (size_t)b * Tc;

#pragma unroll
    for (int i = 0; i < Tc / 256; ++i) {
        const int pos = i * 256 + wave * 64 + lane;
        const unsigned long long m = __ballot(row[pos] & 1);
        if (lane == 0) {
            const int w64 = i * 4 + wave;
            bits[w64 * 2]     = (uint32_t)m;
            bits[w64 * 2 + 1] = (uint32_t)(m >> 32);
        }
    }
    __syncthreads();

    int vals[Nc / 256];
#pragma unroll
    for (int i = 0; i < Nc / 256; ++i) {
        const int n = i * 256 + tid;
        const int4* cp = (const int4*)(connections + n * Kc);
        const int4 c0 = cp[0], c1 = cp[1], c2 = cp[2], c3 = cp[3];
        const int c[16] = {c0.x, c0.y, c0.z, c0.w,
                           c1.x, c1.y, c1.z, c1.w,
                           c2.x, c2.y, c2.z, c2.w,
                           c3.x, c3.y, c3.z, c3.w};
        uint32_t a = 0;
#pragma unroll
        for (int k = 0; k < 16; ++k) {
            const uint32_t t = (uint32_t)c[k];
            a |= ((bits[t >> 5] >> (t & 31)) & 1u) << k;
        }
        vals[i] = __builtin_nontemporal_load(memory + ((size_t)n << 16) + a);
    }

#pragma unroll
    for (int i = 0; i < Nc / 256; ++i) {
        __builtin_nontemporal_store(vals[i] & 1,
                                    out + (size_t)b * Nc + i * 256 + tid);
    }
}

extern "C" void kernel_launch(void* const* d_in, const int* in_sizes, int n_in,
                              void* d_out, int out_size, void* d_ws, size_t ws_size,
                              hipStream_t stream) {
    const int* input_bits  = (const int*)d_in[0];  // B*T
    const int* connections = (const int*)d_in[1];  // N*K
    const int* memory      = (const int*)d_in[2];  // N*M
    int* out               = (int*)d_out;          // B*N (bool -> int32)

    const size_t addr_bytes = (size_t)Bc * Nc * sizeof(unsigned short); // 4 MB

    if (ws_size >= addr_bytes) {
        unsigned short* addr = (unsigned short*)d_ws;
        hipLaunchKernelGGL(addr_kernel, dim3(Bc), dim3(256), 0, stream,
                           input_bits, connections, addr);
        hipLaunchKernelGGL(probe_kernel, dim3(GRID_B), dim3(256), 0, stream,
                           memory, addr, out);
    } else {
        hipLaunchKernelGGL(ram_lookup_fused, dim3(Bc), dim3(256), 0, stream,
                           input_bits, connections, memory, out);
    }
}